// Round 1
// baseline (25.021 us; speedup 1.0000x reference)
//
#include <hip/hip_runtime.h>

#define NPAIRS 460
#define NCLASS 10
#define PIX    3072
#define BATCH  1024

__global__ __launch_bounds__(256) void
qmembership_kernel(const float* __restrict__ x,
                   const float* __restrict__ theta,
                   const int*   __restrict__ pidx,
                   float* __restrict__ out,
                   int total)
{
    __shared__ float s_ct[NCLASS];
    __shared__ float s_st[NCLASS];
    if (threadIdx.x < NCLASS) {
        float t = theta[threadIdx.x];
        float s, c;
        __sincosf(t, &s, &c);   // full angle: cos(theta), sin(theta)
        s_ct[threadIdx.x] = c;
        s_st[threadIdx.x] = s;
    }
    __syncthreads();

    int gid = blockIdx.x * blockDim.x + threadIdx.x;
    if (gid >= total) return;

    int b = gid / NPAIRS;                 // batch index
    // coalesced 8B load of the pair indices
    const int2 pi = ((const int2*)pidx)[gid];

    const float* xb = x + (size_t)b * PIX;
    float av = xb[pi.x];                  // gather within 12KB hot-set -> L1
    float bv = xb[pi.y];

    float sa, ca, sb, cb;
    __sincosf(av, &sa, &ca);
    __sincosf(bv, &sb, &cb);

    // z1 = cos(a)*cos(b)  (class-independent)
    // z0_c = cos(theta_c)*cos(a) - sin(theta_c)*sin(a)*sin(b)
    float sasb = sa * sb;
    float o1   = fmaf(0.5f, ca * cb, 0.5f);

    float o0[NCLASS];
#pragma unroll
    for (int c = 0; c < NCLASS; ++c) {
        float z0 = s_ct[c] * ca - s_st[c] * sasb;
        o0[c] = fmaf(0.5f, z0, 0.5f);
    }

    // output layout [B, P, 2, C] -> 20 contiguous floats per (b,p), 16B aligned
    float4* outp = (float4*)(out + (size_t)gid * 20);
    outp[0] = make_float4(o0[0], o0[1], o0[2], o0[3]);
    outp[1] = make_float4(o0[4], o0[5], o0[6], o0[7]);
    outp[2] = make_float4(o0[8], o0[9], o1, o1);
    outp[3] = make_float4(o1, o1, o1, o1);
    outp[4] = make_float4(o1, o1, o1, o1);
}

extern "C" void kernel_launch(void* const* d_in, const int* in_sizes, int n_in,
                              void* d_out, int out_size, void* d_ws, size_t ws_size,
                              hipStream_t stream) {
    const float* x     = (const float*)d_in[0];
    const float* theta = (const float*)d_in[1];
    const int*   pidx  = (const int*)d_in[2];
    float* out = (float*)d_out;

    const int total = BATCH * NPAIRS;          // 471040
    const int block = 256;
    const int grid  = (total + block - 1) / block;  // 1840
    qmembership_kernel<<<grid, block, 0, stream>>>(x, theta, pidx, out, total);
}

// Round 2
// 15.159 us; speedup vs baseline: 1.6506x; 1.6506x over previous
//
#include <hip/hip_runtime.h>

#define NPAIRS 460
#define NCLASS 10
#define PIX    3072
#define BATCH  1024
#define TPB    512
#define OPAD   21          // padded LDS stride for 20 outputs (gcd(21,32)=1)

__global__ __launch_bounds__(TPB) void
qmem_kernel(const float* __restrict__ x,
            const float* __restrict__ theta,
            const int2*  __restrict__ pidx,
            float* __restrict__ out)
{
    __shared__ float s_x[PIX];                 // 12 KB: one batch row
    __shared__ float s_out[NPAIRS * OPAD];     // 38.6 KB: staged outputs
    __shared__ float s_ct[NCLASS], s_st[NCLASS];

    const int b = blockIdx.x;
    const int t = threadIdx.x;

    // ---- stage x[b] into LDS, coalesced float2 (1536 float2 / 512 threads = 3 each)
    const float2* xrow = (const float2*)(x + (size_t)b * PIX);
#pragma unroll
    for (int i = 0; i < 3; ++i) {
        int j = t + i * TPB;
        float2 v = xrow[j];
        s_x[2 * j]     = v.x;
        s_x[2 * j + 1] = v.y;
    }
    if (t < NCLASS) {
        float s, c;
        __sincosf(theta[t], &s, &c);   // cos(theta), sin(theta) of the FULL angle
        s_ct[t] = c;
        s_st[t] = s;
    }
    __syncthreads();

    // ---- one pair per thread (threads 460..511 idle here)
    if (t < NPAIRS) {
        int2 pi = pidx[(size_t)b * NPAIRS + t];
        float av = s_x[pi.x];
        float bv = s_x[pi.y];
        float sa, ca, sb, cb;
        __sincosf(av, &sa, &ca);
        __sincosf(bv, &sb, &cb);
        // z1 = cos(a)cos(b); z0_c = cos(th_c)cos(a) - sin(th_c)sin(a)sin(b)
        float sasb = sa * sb;
        float o1   = fmaf(0.5f, ca * cb, 0.5f);
        float* po  = s_out + t * OPAD;
#pragma unroll
        for (int c = 0; c < NCLASS; ++c)
            po[c] = fmaf(0.5f, s_ct[c] * ca - s_st[c] * sasb, 0.5f);
#pragma unroll
        for (int c = NCLASS; c < 2 * NCLASS; ++c)
            po[c] = o1;
    }
    __syncthreads();

    // ---- coalesced writeback: 9200 floats = 2300 float4 per row.
    // A float4 never crosses a pair boundary (20 % 4 == 0):
    //   float4 j -> pair p = j/5, elem k = (j%5)*4, LDS addr p*OPAD + k
    float4* og = (float4*)(out + (size_t)b * (NPAIRS * 2 * NCLASS));
    for (int j = t; j < NPAIRS * 5; j += TPB) {
        int p = j / 5;
        int k = (j - p * 5) * 4;
        const float* ps = s_out + p * OPAD + k;
        og[j] = make_float4(ps[0], ps[1], ps[2], ps[3]);
    }
}

extern "C" void kernel_launch(void* const* d_in, const int* in_sizes, int n_in,
                              void* d_out, int out_size, void* d_ws, size_t ws_size,
                              hipStream_t stream) {
    const float* x     = (const float*)d_in[0];
    const float* theta = (const float*)d_in[1];
    const int2*  pidx  = (const int2*)d_in[2];
    float* out = (float*)d_out;

    qmem_kernel<<<BATCH, TPB, 0, stream>>>(x, theta, pidx, out);
}

// Round 3
// 14.979 us; speedup vs baseline: 1.6704x; 1.0120x over previous
//
#include <hip/hip_runtime.h>

#define NPAIRS 460
#define NCLASS 10
#define PIX    3072
#define BATCH  1024
#define TPB    512
#define NF4    (NPAIRS * 5)    // 2300 float4 per batch row

__global__ __launch_bounds__(TPB) void
qmem_kernel(const float* __restrict__ x,
            const float* __restrict__ theta,
            const int2*  __restrict__ pidx,
            float4* __restrict__ out)
{
    __shared__ float s_x[PIX];        // 12 KB: one batch row of pixels
    __shared__ int2  s_pi[NPAIRS];    // 3.7 KB: this row's pair indices
    __shared__ float s_ct[NCLASS], s_st[NCLASS];

    const int b = blockIdx.x;
    const int t = threadIdx.x;

    // ---- stage x[b] into LDS, coalesced float2 (1536 / 512 = 3 each)
    const float2* xrow = (const float2*)(x + (size_t)b * PIX);
#pragma unroll
    for (int i = 0; i < 3; ++i) {
        int j = t + i * TPB;
        float2 v = xrow[j];
        s_x[2 * j]     = v.x;
        s_x[2 * j + 1] = v.y;
    }
    // ---- stage pair indices, coalesced
    const int2* prow = pidx + (size_t)b * NPAIRS;
    if (t < NPAIRS) s_pi[t] = prow[t];
    if (t < NCLASS) {
        float s, c;
        __sincosf(theta[t], &s, &c);   // full-angle cos(theta), sin(theta)
        s_ct[t] = c;
        s_st[t] = s;
    }
    __syncthreads();

    // ---- each thread owns consecutive output float4s: perfectly coalesced stores.
    // float4 j -> pair p = j/5, elems k..k+3 with k = (j%5)*4.
    float4* og = out + (size_t)b * NF4;
    for (int j = t; j < NF4; j += TPB) {
        int p = j / 5;
        int k = (j - p * 5) * 4;       // 0,4,8,12,16
        int2 pi = s_pi[p];
        float sa, ca, sb, cb;
        __sincosf(s_x[pi.x], &sa, &ca);
        __sincosf(s_x[pi.y], &sb, &cb);
        float sasb = sa * sb;
        float o1   = fmaf(0.5f, ca * cb, 0.5f);   // (z1+1)/2, class-independent

        float4 v;
        float* vp = (float*)&v;
#pragma unroll
        for (int e = 0; e < 4; ++e) {
            int c = k + e;             // output channel 0..19
            if (c < NCLASS) {
                vp[e] = fmaf(0.5f, s_ct[c] * ca - s_st[c] * sasb, 0.5f);
            } else {
                vp[e] = o1;
            }
        }
        og[j] = v;
    }
}

extern "C" void kernel_launch(void* const* d_in, const int* in_sizes, int n_in,
                              void* d_out, int out_size, void* d_ws, size_t ws_size,
                              hipStream_t stream) {
    const float* x     = (const float*)d_in[0];
    const float* theta = (const float*)d_in[1];
    const int2*  pidx  = (const int2*)d_in[2];
    float4* out = (float4*)d_out;

    qmem_kernel<<<BATCH, TPB, 0, stream>>>(x, theta, pidx, out);
}